// Round 5
// baseline (885.820 us; speedup 1.0000x reference)
//
#include <hip/hip_runtime.h>

// SearchTransfer: patch cosine-sim argmax + multi-level gather/fold.
// rel = 9-tap diagonal-shift sum of pixel Gram S (K=256); transfer == gather.
// This round: U = dx-folded S produced in the GEMM epilogue (stride-126
// overlapped tiles, never materialize S); 3-tap argmax on U with 4x4 query
// tiles + key-split; near-tie-only exact rescore (k_pick).

#define HW3 2304
#define PLANE 589824        // 256*2304
#define MP 2560             // padded+rounded grid (50x50=2500 -> 2560)
#define KP 512              // bf16 plane: hi[256] | lo[256]

typedef __bf16 v8bf __attribute__((ext_vector_type(8)));
typedef float v16f __attribute__((ext_vector_type(16)));

// ws float offsets
#define O_PSI  0
#define O_PSR  9216
#define O_IKN  18432
#define O_IQN  27648
#define O_RIDX 36864        // int[9216]
#define O_IKNP 46080        // float[4*2560], NaN at pads
#define O_CAND 56320        // int[4*2304*4]
#define O_CANDV 93184       // float[4*2304*4]
#define O_IMGT 130048       // float[4*2304*256]
#define O_REFT 2489344
#define O_APL  4848640      // __bf16[4*2560*512] == 2621440 float slots
#define O_BPL  7470080
#define O_U    10091520     // float[nb*2560*2560]

// ---- per-pixel sum of squares (coalesced: 64 pixels x 4 channel groups) ----
__global__ __launch_bounds__(256) void k_pixsq(const float* __restrict__ img,
                                               const float* __restrict__ ref,
                                               float* __restrict__ psi,
                                               float* __restrict__ psr) {
  __shared__ float ri[4][64], rr[4][64];
  const int t = threadIdx.x, lane = t & 63, cg = t >> 6;
  const int pix = blockIdx.x * 64 + lane;     // [0, 9216)
  const int b = pix / HW3, p = pix - b * HW3;
  const float* ib = img + (size_t)b * PLANE + p;
  const float* rb = ref + (size_t)b * PLANE + p;
  float si = 0.f, sr = 0.f;
#pragma unroll 8
  for (int c = 0; c < 64; ++c) {
    float x = ib[(cg * 64 + c) * HW3]; si = fmaf(x, x, si);
    float y = rb[(cg * 64 + c) * HW3]; sr = fmaf(y, y, sr);
  }
  ri[cg][lane] = si; rr[cg][lane] = sr;
  __syncthreads();
  if (t < 64) {
    float a = ri[0][t] + ri[1][t] + ri[2][t] + ri[3][t];
    float s2 = rr[0][t] + rr[1][t] + rr[2][t] + rr[3][t];
    psi[blockIdx.x * 64 + t] = a; psr[blockIdx.x * 64 + t] = s2;
  }
}

// ---- 3x3 box sum -> reciprocal patch norms (valid-indexed) ----
__global__ __launch_bounds__(256) void k_norm(const float* __restrict__ psr,
                                              const float* __restrict__ psi,
                                              float* __restrict__ ikn,
                                              float* __restrict__ iqn) {
  int pix = blockIdx.x * 256 + threadIdx.x;
  int b = pix / HW3, p = pix - b * HW3;
  int py = p / 48, px = p - py * 48;
  float sr = 0.f, si = 0.f;
#pragma unroll
  for (int dy = -1; dy <= 1; ++dy)
#pragma unroll
    for (int dx = -1; dx <= 1; ++dx) {
      if (py + dy < 0 || py + dy >= 48 || px + dx < 0 || px + dx >= 48) continue;
      int n = pix + dy * 48 + dx;
      sr += psr[n]; si += psi[n];
    }
  ikn[pix] = 1.0f / fmaxf(sqrtf(sr), 1e-12f);
  iqn[pix] = 1.0f / fmaxf(sqrtf(si), 1e-12f);
}

// ---- padded reciprocal key norms: NaN at pad positions (never win argmax) ----
__global__ __launch_bounds__(256) void k_normp(const float* __restrict__ psr,
                                               float* __restrict__ iknp) {
  int idx = blockIdx.x * 256 + threadIdx.x;   // [0, 4*2560)
  int b = idx / MP, pp = idx - b * MP;
  int py = pp / 50, px = pp - py * 50;
  float r = __uint_as_float(0x7fc00000u);     // NaN
  if (pp < 2500 && py != 0 && py != 49 && px != 0 && px != 49) {
    int y = py - 1, x = px - 1;
    float s = 0.f;
    for (int dy = -1; dy <= 1; ++dy)
      for (int dx = -1; dx <= 1; ++dx) {
        int yy = y + dy, xx = x + dx;
        if (yy >= 0 && yy < 48 && xx >= 0 && xx < 48)
          s += psr[b * HW3 + yy * 48 + xx];
      }
    r = 1.0f / fmaxf(sqrtf(s), 1e-12f);
  }
  iknp[idx] = r;
}

// ---- transpose+pad+bf16-split: [C][2304] -> [2560 padded pix][hi|lo] ----
__global__ __launch_bounds__(256) void k_padsplit(const float* __restrict__ src,
                                                  __bf16* __restrict__ dst) {
  __shared__ float sm[64][65];
  const int pix0 = blockIdx.x * 64, c0 = blockIdx.y * 64, b = blockIdx.z;
  const int lane = threadIdx.x & 63, q4 = threadIdx.x >> 6;
  const float* s = src + (size_t)b * PLANE;
#pragma unroll
  for (int r = 0; r < 16; ++r) {
    int cl = r * 4 + q4;
    sm[cl][lane] = s[(size_t)(c0 + cl) * HW3 + pix0 + lane];
  }
  __syncthreads();
  __bf16* d = dst + (size_t)b * MP * KP;
#pragma unroll
  for (int r = 0; r < 16; ++r) {
    int pl = r * 4 + q4;
    int p = pix0 + pl;
    int py = p / 48, px = p - py * 48;
    int pp = (py + 1) * 50 + px + 1;
    float v = sm[lane][pl];
    __bf16 hi = (__bf16)v;
    __bf16 lo = (__bf16)(v - (float)hi);
    d[(size_t)pp * KP + c0 + lane] = hi;
    d[(size_t)pp * KP + 256 + c0 + lane] = lo;
  }
}

// ---- plain tiled transpose [C][HW] -> [HW][C] ----
__global__ __launch_bounds__(256) void k_tr(const float* __restrict__ src,
                                            float* __restrict__ dst,
                                            int C, int HW, int b0) {
  __shared__ float sm[64][65];
  int pix0 = blockIdx.x * 64, c0 = blockIdx.y * 64;
  const float* s = src + (size_t)(b0 + blockIdx.z) * C * HW;
  float* d = dst + (size_t)blockIdx.z * HW * C;
  int lane = threadIdx.x & 63, q4 = threadIdx.x >> 6;
#pragma unroll
  for (int r = 0; r < 16; ++r) {
    int cl = r * 4 + q4;
    sm[cl][lane] = s[(size_t)(c0 + cl) * HW + pix0 + lane];
  }
  __syncthreads();
#pragma unroll
  for (int r = 0; r < 16; ++r) {
    int pl = r * 4 + q4;
    d[(size_t)(pix0 + pl) * C + c0 + lane] = sm[lane][pl];
  }
}

// ---- split-bf16 MFMA GEMM + fused U epilogue ----
// Stride-126 overlapped tiles: compute S 128x128 (rows/cols q0..q0+127 with
// q0 = 126*by-1, OOB rows -> 0), emit U interior (rows/cols q0+1..q0+126):
// U[q][p] = S[q-1][p-1] + S[q][p] + S[q+1][p+1].
__global__ __launch_bounds__(256) void k_gemm_u(const __bf16* __restrict__ Apl,
                                                const __bf16* __restrict__ Bpl,
                                                float* __restrict__ U, int b0) {
  __shared__ __align__(16) char smem[36864];
  __bf16 (*As)[72] = (__bf16(*)[72])smem;
  __bf16 (*Bs)[72] = (__bf16(*)[72])(smem + 18432);
  const int b = b0 + blockIdx.z;
  const __bf16* Ab = Apl + (size_t)b * MP * KP;
  const __bf16* Bb = Bpl + (size_t)b * MP * KP;
  float* Ub = U + (size_t)blockIdx.z * (2560LL * 2560LL);
  const int t = threadIdx.x;
  const int q0 = blockIdx.y * 126 - 1, p0 = blockIdx.x * 126 - 1;
  const int lane = t & 63, w = t >> 6, wr = w >> 1, wc = w & 1;
  const int sr = t >> 1, ss = (t & 1) * 32;
  const int l31 = lane & 31, kb = (lane >> 5) * 8;
  const int arow = q0 + sr, brow = p0 + sr;
  const bool aok = (unsigned)arow < 2560u, bok = (unsigned)brow < 2560u;

  v16f acc[2][2];
#pragma unroll
  for (int i = 0; i < 2; ++i)
#pragma unroll
    for (int j = 0; j < 2; ++j)
#pragma unroll
      for (int e = 0; e < 16; ++e) acc[i][j][e] = 0.f;

  const float4 z4 = make_float4(0.f, 0.f, 0.f, 0.f);
  for (int kv = 0; kv < 768; kv += 64) {
    const int ak = kv < 256 ? kv : kv - 256;   // Ahi, Ahi, Alo
    const int bk = kv < 512 ? kv : kv - 512;   // Bhi, Blo, Bhi
    const __bf16* ga = Ab + (size_t)arow * KP + ak + ss;
    const __bf16* gb = Bb + (size_t)brow * KP + bk + ss;
    float4 a0 = aok ? *(const float4*)(ga)      : z4;
    float4 a1 = aok ? *(const float4*)(ga + 8)  : z4;
    float4 a2 = aok ? *(const float4*)(ga + 16) : z4;
    float4 a3 = aok ? *(const float4*)(ga + 24) : z4;
    float4 b0v = bok ? *(const float4*)(gb)      : z4;
    float4 b1v = bok ? *(const float4*)(gb + 8)  : z4;
    float4 b2v = bok ? *(const float4*)(gb + 16) : z4;
    float4 b3v = bok ? *(const float4*)(gb + 24) : z4;
    __syncthreads();
    *(float4*)(&As[sr][ss])      = a0;
    *(float4*)(&As[sr][ss + 8])  = a1;
    *(float4*)(&As[sr][ss + 16]) = a2;
    *(float4*)(&As[sr][ss + 24]) = a3;
    *(float4*)(&Bs[sr][ss])      = b0v;
    *(float4*)(&Bs[sr][ss + 8])  = b1v;
    *(float4*)(&Bs[sr][ss + 16]) = b2v;
    *(float4*)(&Bs[sr][ss + 24]) = b3v;
    __syncthreads();
#pragma unroll
    for (int kk = 0; kk < 4; ++kk) {
      const int ko = kk * 16 + kb;
      v8bf af0 = *(const v8bf*)(&As[wr * 64 + l31][ko]);
      v8bf af1 = *(const v8bf*)(&As[wr * 64 + 32 + l31][ko]);
      v8bf bg0 = *(const v8bf*)(&Bs[wc * 64 + l31][ko]);
      v8bf bg1 = *(const v8bf*)(&Bs[wc * 64 + 32 + l31][ko]);
      acc[0][0] = __builtin_amdgcn_mfma_f32_32x32x16_bf16(af0, bg0, acc[0][0], 0, 0, 0);
      acc[0][1] = __builtin_amdgcn_mfma_f32_32x32x16_bf16(af0, bg1, acc[0][1], 0, 0, 0);
      acc[1][0] = __builtin_amdgcn_mfma_f32_32x32x16_bf16(af1, bg0, acc[1][0], 0, 0, 0);
      acc[1][1] = __builtin_amdgcn_mfma_f32_32x32x16_bf16(af1, bg1, acc[1][1], 0, 0, 0);
    }
  }

  // ---- epilogue: dump S tile to LDS in 65-row halves, emit U interior ----
  float (*Sd)[128] = (float(*)[128])smem;
#pragma unroll
  for (int h = 0; h < 2; ++h) {
    const int rlo = h * 63;
    __syncthreads();
#pragma unroll
    for (int mf = 0; mf < 2; ++mf)
#pragma unroll
      for (int nf = 0; nf < 2; ++nf) {
        const int col = wc * 64 + nf * 32 + l31;
#pragma unroll
        for (int r16 = 0; r16 < 16; ++r16) {
          const int row = wr * 64 + mf * 32 + (r16 & 3) + 8 * (r16 >> 2) + 4 * (lane >> 5);
          const int lr = row - rlo;
          if (lr >= 0 && lr < 65) Sd[lr][col] = acc[mf][nf][r16];
        }
      }
    __syncthreads();
    for (int idx = t; idx < 63 * 126; idx += 256) {
      const int lr = idx / 126 + 1;           // 1..63
      const int ce = idx - (lr - 1) * 126 + 1; // 1..126
      const int gq = q0 + rlo + lr;
      const int gp = p0 + ce;
      if ((unsigned)gq < 2560u && (unsigned)gp < 2560u)
        Ub[(size_t)gq * 2560 + gp] = Sd[lr - 1][ce - 1] + Sd[lr][ce] + Sd[lr + 1][ce + 1];
    }
  }
}

// ---- 3-tap argmax on U: 4x4 query tile, half the keys, top-2 per query ----
__global__ __launch_bounds__(256) void k_argmax_u(const float* __restrict__ U,
                                                  const float* __restrict__ iknp,
                                                  int* __restrict__ cand,
                                                  float* __restrict__ candv, int b0) {
  __shared__ float Lu[24][356];
  __shared__ float smv[16][4][2];
  __shared__ int   smi[16][4][2];
  const int zb = blockIdx.z >> 1, half = blockIdx.z & 1;
  const int b = b0 + zb;
  const float* Ub = U + (size_t)zb * (2560LL * 2560LL);
  const int qy0 = blockIdx.y * 4, qx0 = blockIdx.x * 4;
  const int kb = half * 1280;
  const int t = threadIdx.x, lane = t & 63, wv = t >> 6;

  float b1[16], b2[16]; int i1[16], i2[16];
#pragma unroll
  for (int i = 0; i < 16; ++i) { b1[i] = -3e38f; b2[i] = -3e38f; i1[i] = 0x3fffffff; i2[i] = 0x3fffffff; }

  for (int ch = 0; ch < 5; ++ch) {
    const int kc = kb + ch * 256;
    for (int rr = wv; rr < 24; rr += 4) {
      const int g = rr >> 2, a = rr & 3;
      const float* src = Ub + (size_t)((qy0 + g) * 50 + qx0 + 1 + a) * 2560;
      float* dst = Lu[rr];
      for (int c = lane; c < 356; c += 64) {
        const int gc = kc - 50 + c;
        dst[c] = ((unsigned)gc < 2560u) ? src[gc] : 0.f;
      }
    }
    __syncthreads();
    const float ikv = iknp[b * MP + kc + t];
    const int p = kc + t;
#pragma unroll
    for (int e = 0; e < 4; ++e)
#pragma unroll
      for (int a = 0; a < 4; ++a) {
        const float rel = Lu[e * 4 + a][t] + Lu[(e + 1) * 4 + a][t + 50] + Lu[(e + 2) * 4 + a][t + 100];
        const float v = rel * ikv;             // NaN at invalid keys -> never wins
        const int qi = e * 4 + a;
        if (v > b1[qi]) { b2[qi] = b1[qi]; i2[qi] = i1[qi]; b1[qi] = v; i1[qi] = p; }
        else if (v > b2[qi]) { b2[qi] = v; i2[qi] = p; }
      }
    __syncthreads();
  }

#pragma unroll
  for (int qi = 0; qi < 16; ++qi) {
    float x1 = b1[qi], x2 = b2[qi]; int j1 = i1[qi], j2 = i2[qi];
#pragma unroll
    for (int off = 32; off; off >>= 1) {
      float o1 = __shfl_down(x1, off), o2 = __shfl_down(x2, off);
      int oj1 = __shfl_down(j1, off), oj2 = __shfl_down(j2, off);
      if (o1 > x1 || (o1 == x1 && oj1 < j1)) {
        float tv = x1; int tj = j1;
        x1 = o1; j1 = oj1;
        if (o2 > tv || (o2 == tv && oj2 < tj)) { x2 = o2; j2 = oj2; }
        else { x2 = tv; j2 = tj; }
      } else if (o1 > x2 || (o1 == x2 && oj1 < j2)) { x2 = o1; j2 = oj1; }
    }
    if (lane == 0) { smv[qi][wv][0] = x1; smv[qi][wv][1] = x2; smi[qi][wv][0] = j1; smi[qi][wv][1] = j2; }
  }
  __syncthreads();
  if (t < 16) {
    float x1 = smv[t][0][0], x2 = smv[t][0][1]; int j1 = smi[t][0][0], j2 = smi[t][0][1];
#pragma unroll
    for (int w2 = 1; w2 < 4; ++w2) {
      float o1 = smv[t][w2][0], o2 = smv[t][w2][1];
      int oj1 = smi[t][w2][0], oj2 = smi[t][w2][1];
      if (o1 > x1 || (o1 == x1 && oj1 < j1)) {
        float tv = x1; int tj = j1;
        x1 = o1; j1 = oj1;
        if (o2 > tv || (o2 == tv && oj2 < tj)) { x2 = o2; j2 = oj2; }
        else { x2 = tv; j2 = tj; }
      } else if (o1 > x2 || (o1 == x2 && oj1 < j2)) { x2 = o1; j2 = oj1; }
    }
    // padded idx -> valid idx
    int my1 = j1 / 50, my2 = j2 / 50;
    int m1 = (my1 - 1) * 48 + (j1 - my1 * 50 - 1);
    int m2 = (my2 - 1) * 48 + (j2 - my2 * 50 - 1);
    const int q = (qy0 + (t >> 2)) * 48 + qx0 + (t & 3);
    const size_t base = ((size_t)b * HW3 + q) * 4 + half * 2;
    cand[base] = m1; cand[base + 1] = m2;
    candv[base] = x1; candv[base + 1] = x2;
  }
}

// ---- final pick: fast path on clear gaps, exact f32 dots only on near-ties ----
__global__ __launch_bounds__(256) void k_pick(const float* __restrict__ imgT,
                                              const float* __restrict__ refT,
                                              const float* __restrict__ ikn,
                                              const float* __restrict__ iqn,
                                              const int* __restrict__ cand,
                                              const float* __restrict__ candv,
                                              int* __restrict__ ridx,
                                              float* __restrict__ outS) {
  const int t = threadIdx.x, lane = t & 63, wv = t >> 6;
  const int qg = blockIdx.x * 4 + wv;
  const int b = qg / HW3, q = qg - b * HW3;
  int ci[4]; float cv[4];
#pragma unroll
  for (int s = 0; s < 4; ++s) { ci[s] = cand[(size_t)qg * 4 + s]; cv[s] = candv[(size_t)qg * 4 + s]; }
  int o1 = 0;
#pragma unroll
  for (int s = 1; s < 4; ++s)
    if (cv[s] > cv[o1] || (cv[s] == cv[o1] && ci[s] < ci[o1])) o1 = s;
  int o2 = -1;
#pragma unroll
  for (int s = 0; s < 4; ++s) {
    if (s == o1) continue;
    if (o2 < 0 || cv[s] > cv[o2] || (cv[s] == cv[o2] && ci[s] < ci[o2])) o2 = s;
  }
  int m1 = ci[o1], m2 = ci[o2];
  float v1 = cv[o1], v2 = cv[o2];
  int win = m1; float wval = v1;
  if (v1 - v2 <= 1e-5f * fmaxf(fabsf(v1), 1.0f)) {
    // exact rescore of m1, m2
    const int qy = q / 48, qx = q - qy * 48;
    const float* iT = imgT + (size_t)b * HW3 * 256;
    const float* rT = refT + (size_t)b * HW3 * 256;
    const int p1y = m1 / 48, p1x = m1 - p1y * 48;
    const int p2y = m2 / 48, p2x = m2 - p2y * 48;
    float s1 = 0.f, s2 = 0.f;
    for (int dy = -1; dy <= 1; ++dy) {
      int yq = qy + dy; if (yq < 0 || yq >= 48) continue;
      for (int dx = -1; dx <= 1; ++dx) {
        int xq = qx + dx; if (xq < 0 || xq >= 48) continue;
        const float* qrow = iT + (size_t)(yq * 48 + xq) * 256;
        int y1 = p1y + dy, x1 = p1x + dx, y2 = p2y + dy, x2 = p2x + dx;
        bool k1 = (y1 >= 0 && y1 < 48 && x1 >= 0 && x1 < 48);
        bool k2 = (y2 >= 0 && y2 < 48 && x2 >= 0 && x2 < 48);
        const float* r1 = rT + (size_t)(k1 ? y1 * 48 + x1 : 0) * 256;
        const float* r2 = rT + (size_t)(k2 ? y2 * 48 + x2 : 0) * 256;
#pragma unroll
        for (int j = 0; j < 4; ++j) {
          float qv = qrow[lane + j * 64];
          if (k1) s1 = fmaf(qv, r1[lane + j * 64], s1);
          if (k2) s2 = fmaf(qv, r2[lane + j * 64], s2);
        }
      }
    }
#pragma unroll
    for (int off = 32; off; off >>= 1) {
      s1 += __shfl_down(s1, off);
      s2 += __shfl_down(s2, off);
    }
    float e1 = s1 * ikn[b * HW3 + m1], e2 = s2 * ikn[b * HW3 + m2];
    if (e2 > e1 || (e2 == e1 && m2 < m1)) { win = m2; wval = e2; }
    else { win = m1; wval = e1; }
  }
  if (lane == 0) {
    ridx[b * HW3 + q] = win;
    outS[qg] = wval * iqn[b * HW3 + q];
  }
}

// ---- gather+fold in channel-last, coalesced, LDS transpose on write ----
__global__ __launch_bounds__(256) void k_foldgather(const float* __restrict__ t,
                                                    const int* __restrict__ ridx,
                                                    float* __restrict__ out,
                                                    int C, int H, int sc, int b0) {
  __shared__ int   soff[64][9];
  __shared__ float sicnt[64];
  __shared__ float tr[64][65];
  const int HW = H * H;
  const int b = b0 + blockIdx.y;
  const float* tb = t + (size_t)blockIdx.y * HW * C;
  const int* rb = ridx + b * HW3;
  const int pix0 = blockIdx.x * 64;

  for (int e = threadIdx.x; e < 576; e += 256) {
    int op = e / 9, tap = e - op * 9;
    int pix = pix0 + op;
    int h = pix / H, w = pix - h * H;
    int hi = h / sc, hr = h - hi * sc;
    int wi = w / sc, wr = w - wi * sc;
    int ii = tap / 3, jj = tap - ii * 3;
    int oy = hi + 1 - ii, ox = wi + 1 - jj;
    int off = -1;
    if (oy >= 0 && oy < 48 && ox >= 0 && ox < 48) {
      int m = rb[oy * 48 + ox];
      int my = m / 48, mx = m - my * 48;
      int y = sc * (my - 1 + ii) + hr;
      int x = sc * (mx - 1 + jj) + wr;
      if (y >= 0 && y < H && x >= 0 && x < H) off = y * H + x;
    }
    soff[op][tap] = off;
    if (tap == 0) {
      int cnt = 0;
#pragma unroll
      for (int i2 = 0; i2 < 3; ++i2)
#pragma unroll
        for (int j2 = 0; j2 < 3; ++j2) {
          int oy2 = hi + 1 - i2, ox2 = wi + 1 - j2;
          if (oy2 >= 0 && oy2 < 48 && ox2 >= 0 && ox2 < 48) ++cnt;
        }
      sicnt[op] = 1.0f / (float)cnt;
    }
  }
  __syncthreads();

  const int g = threadIdx.x >> 6, lane = threadIdx.x & 63;
  for (int c0 = 0; c0 < C; c0 += 64) {
#pragma unroll
    for (int o = 0; o < 16; ++o) {
      int op = g * 16 + o;
      float s = 0.f;
#pragma unroll
      for (int tp = 0; tp < 9; ++tp) {
        int off = soff[op][tp];
        if (off >= 0) s += tb[(size_t)off * C + c0 + lane];
      }
      tr[op][lane] = s * sicnt[op];
    }
    __syncthreads();
#pragma unroll
    for (int r = 0; r < 16; ++r) {
      int cl = r * 4 + g;
      out[((size_t)b * C + c0 + cl) * HW + pix0 + lane] = tr[lane][cl];
    }
    __syncthreads();
  }
}

extern "C" void kernel_launch(void* const* d_in, const int* in_sizes, int n_in,
                              void* d_out, int out_size, void* d_ws, size_t ws_size,
                              hipStream_t stream) {
  (void)in_sizes; (void)n_in; (void)out_size;
  const float* img = (const float*)d_in[0];
  const float* ref = (const float*)d_in[1];
  const float* cl1 = (const float*)d_in[2];   // [4,64,192,192]
  const float* cl2 = (const float*)d_in[3];   // [4,128,96,96]
  const float* cl3 = (const float*)d_in[4];   // [4,256,48,48]
  float* out = (float*)d_out;

  float* ws   = (float*)d_ws;
  float* ps_i = ws + O_PSI;
  float* ps_r = ws + O_PSR;
  float* ikn  = ws + O_IKN;
  float* iqn  = ws + O_IQN;
  int*   ridx = (int*)(ws + O_RIDX);
  float* iknp = ws + O_IKNP;
  int*   cand = (int*)(ws + O_CAND);
  float* candv = ws + O_CANDV;
  float* imgT = ws + O_IMGT;
  float* refT = ws + O_REFT;
  __bf16* Apl = (__bf16*)(ws + O_APL);
  __bf16* Bpl = (__bf16*)(ws + O_BPL);
  float* Um   = ws + O_U;

  // zero bf16 planes (pad pixels must be 0)
  hipMemsetAsync(ws + O_APL, 0, (size_t)(O_U - O_APL) * 4, stream);

  k_pixsq<<<144, 256, 0, stream>>>(img, ref, ps_i, ps_r);
  k_norm<<<36, 256, 0, stream>>>(ps_r, ps_i, ikn, iqn);
  k_normp<<<40, 256, 0, stream>>>(ps_r, iknp);
  k_padsplit<<<dim3(36, 4, 4), 256, 0, stream>>>(img, Apl);
  k_padsplit<<<dim3(36, 4, 4), 256, 0, stream>>>(ref, Bpl);
  k_tr<<<dim3(36, 4, 4), 256, 0, stream>>>(img, imgT, 256, HW3, 0);
  k_tr<<<dim3(36, 4, 4), 256, 0, stream>>>(ref, refT, 256, HW3, 0);

  const long long UPF = 2560LL * 2560LL;
  const long long availf = (long long)(ws_size / 4) - O_U;
  const int nb = (availf >= 4 * UPF) ? 4 : ((availf >= 2 * UPF) ? 2 : 1);
  for (int g = 0; g < 4; g += nb) {
    k_gemm_u<<<dim3(21, 21, nb), 256, 0, stream>>>(Apl, Bpl, Um, g);
    k_argmax_u<<<dim3(12, 12, nb * 2), 256, 0, stream>>>(Um, iknp, cand, candv, g);
  }
  k_pick<<<2304, 256, 0, stream>>>(imgT, refT, ikn, iqn, cand, candv, ridx, out);

  // folds (scratch reuses imgT.. region; search inputs dead by now)
  float* t = ws + O_IMGT;
  k_tr<<<dim3(36, 4, 4), 256, 0, stream>>>(cl3, t, 256, 2304, 0);
  k_foldgather<<<dim3(36, 4), 256, 0, stream>>>(t, ridx, out + 9216, 256, 48, 1, 0);
  k_tr<<<dim3(144, 2, 4), 256, 0, stream>>>(cl2, t, 128, 9216, 0);
  k_foldgather<<<dim3(144, 4), 256, 0, stream>>>(t, ridx, out + 2368512, 128, 96, 2, 0);
  k_tr<<<dim3(576, 1, 4), 256, 0, stream>>>(cl1, t, 64, 36864, 0);
  k_foldgather<<<dim3(576, 4), 256, 0, stream>>>(t, ridx, out + 7087104, 64, 192, 4, 0);
}

// Round 6
// 757.152 us; speedup vs baseline: 1.1699x; 1.1699x over previous
//
#include <hip/hip_runtime.h>

// SearchTransfer: patch cosine-sim argmax + multi-level gather/fold.
// rel = 9-tap diagonal-shift sum of pixel Gram S (K=256); transfer == gather.
// U = dx-folded S from the GEMM epilogue; rel[q][p] = sum_dy U[qp+50dy][p+50dy].
// This round: argmax rewritten as barrier-free LDS-free direct-read scan
// (48 const-offset coalesced loads per chunk, 5-way key split).

#define HW3 2304
#define PLANE 589824        // 256*2304
#define MP 2560             // padded+rounded grid (50x50=2500 -> 2560)
#define KP 512              // bf16 plane: hi[256] | lo[256]

typedef __bf16 v8bf __attribute__((ext_vector_type(8)));
typedef float v16f __attribute__((ext_vector_type(16)));

// ws float offsets
#define O_PSI  0
#define O_PSR  9216
#define O_IKN  18432
#define O_IQN  27648
#define O_RIDX 36864        // int[9216]
#define O_IKNP 46080        // float[4*2560], NaN at pads
#define O_CAND 56320        // int[4*2304*10]
#define O_CANDV 148480      // float[4*2304*10]
#define O_IMGT 240640       // float[4*2304*256]
#define O_REFT 2599936
#define O_APL  4959232      // __bf16[4*2560*512] == 2621440 float slots
#define O_BPL  7580672
#define O_U    10202112     // float[nb*2560*2560]

// ---- per-pixel sum of squares (coalesced: 64 pixels x 4 channel groups) ----
__global__ __launch_bounds__(256) void k_pixsq(const float* __restrict__ img,
                                               const float* __restrict__ ref,
                                               float* __restrict__ psi,
                                               float* __restrict__ psr) {
  __shared__ float ri[4][64], rr[4][64];
  const int t = threadIdx.x, lane = t & 63, cg = t >> 6;
  const int pix = blockIdx.x * 64 + lane;     // [0, 9216)
  const int b = pix / HW3, p = pix - b * HW3;
  const float* ib = img + (size_t)b * PLANE + p;
  const float* rb = ref + (size_t)b * PLANE + p;
  float si = 0.f, sr = 0.f;
#pragma unroll 8
  for (int c = 0; c < 64; ++c) {
    float x = ib[(cg * 64 + c) * HW3]; si = fmaf(x, x, si);
    float y = rb[(cg * 64 + c) * HW3]; sr = fmaf(y, y, sr);
  }
  ri[cg][lane] = si; rr[cg][lane] = sr;
  __syncthreads();
  if (t < 64) {
    float a = ri[0][t] + ri[1][t] + ri[2][t] + ri[3][t];
    float s2 = rr[0][t] + rr[1][t] + rr[2][t] + rr[3][t];
    psi[blockIdx.x * 64 + t] = a; psr[blockIdx.x * 64 + t] = s2;
  }
}

// ---- 3x3 box sum -> reciprocal patch norms (valid-indexed) ----
__global__ __launch_bounds__(256) void k_norm(const float* __restrict__ psr,
                                              const float* __restrict__ psi,
                                              float* __restrict__ ikn,
                                              float* __restrict__ iqn) {
  int pix = blockIdx.x * 256 + threadIdx.x;
  int b = pix / HW3, p = pix - b * HW3;
  int py = p / 48, px = p - py * 48;
  float sr = 0.f, si = 0.f;
#pragma unroll
  for (int dy = -1; dy <= 1; ++dy)
#pragma unroll
    for (int dx = -1; dx <= 1; ++dx) {
      if (py + dy < 0 || py + dy >= 48 || px + dx < 0 || px + dx >= 48) continue;
      int n = pix + dy * 48 + dx;
      sr += psr[n]; si += psi[n];
    }
  ikn[pix] = 1.0f / fmaxf(sqrtf(sr), 1e-12f);
  iqn[pix] = 1.0f / fmaxf(sqrtf(si), 1e-12f);
}

// ---- padded reciprocal key norms: NaN at pad positions (never win argmax) ----
__global__ __launch_bounds__(256) void k_normp(const float* __restrict__ psr,
                                               float* __restrict__ iknp) {
  int idx = blockIdx.x * 256 + threadIdx.x;   // [0, 4*2560)
  int b = idx / MP, pp = idx - b * MP;
  int py = pp / 50, px = pp - py * 50;
  float r = __uint_as_float(0x7fc00000u);     // NaN
  if (pp < 2500 && py != 0 && py != 49 && px != 0 && px != 49) {
    int y = py - 1, x = px - 1;
    float s = 0.f;
    for (int dy = -1; dy <= 1; ++dy)
      for (int dx = -1; dx <= 1; ++dx) {
        int yy = y + dy, xx = x + dx;
        if (yy >= 0 && yy < 48 && xx >= 0 && xx < 48)
          s += psr[b * HW3 + yy * 48 + xx];
      }
    r = 1.0f / fmaxf(sqrtf(s), 1e-12f);
  }
  iknp[idx] = r;
}

// ---- transpose+pad+bf16-split: [C][2304] -> [2560 padded pix][hi|lo] ----
__global__ __launch_bounds__(256) void k_padsplit(const float* __restrict__ src,
                                                  __bf16* __restrict__ dst) {
  __shared__ float sm[64][65];
  const int pix0 = blockIdx.x * 64, c0 = blockIdx.y * 64, b = blockIdx.z;
  const int lane = threadIdx.x & 63, q4 = threadIdx.x >> 6;
  const float* s = src + (size_t)b * PLANE;
#pragma unroll
  for (int r = 0; r < 16; ++r) {
    int cl = r * 4 + q4;
    sm[cl][lane] = s[(size_t)(c0 + cl) * HW3 + pix0 + lane];
  }
  __syncthreads();
  __bf16* d = dst + (size_t)b * MP * KP;
#pragma unroll
  for (int r = 0; r < 16; ++r) {
    int pl = r * 4 + q4;
    int p = pix0 + pl;
    int py = p / 48, px = p - py * 48;
    int pp = (py + 1) * 50 + px + 1;
    float v = sm[lane][pl];
    __bf16 hi = (__bf16)v;
    __bf16 lo = (__bf16)(v - (float)hi);
    d[(size_t)pp * KP + c0 + lane] = hi;
    d[(size_t)pp * KP + 256 + c0 + lane] = lo;
  }
}

// ---- plain tiled transpose [C][HW] -> [HW][C] ----
__global__ __launch_bounds__(256) void k_tr(const float* __restrict__ src,
                                            float* __restrict__ dst,
                                            int C, int HW, int b0) {
  __shared__ float sm[64][65];
  int pix0 = blockIdx.x * 64, c0 = blockIdx.y * 64;
  const float* s = src + (size_t)(b0 + blockIdx.z) * C * HW;
  float* d = dst + (size_t)blockIdx.z * HW * C;
  int lane = threadIdx.x & 63, q4 = threadIdx.x >> 6;
#pragma unroll
  for (int r = 0; r < 16; ++r) {
    int cl = r * 4 + q4;
    sm[cl][lane] = s[(size_t)(c0 + cl) * HW + pix0 + lane];
  }
  __syncthreads();
#pragma unroll
  for (int r = 0; r < 16; ++r) {
    int pl = r * 4 + q4;
    d[(size_t)(pix0 + pl) * C + c0 + lane] = sm[lane][pl];
  }
}

// ---- split-bf16 MFMA GEMM + fused U epilogue ----
__global__ __launch_bounds__(256) void k_gemm_u(const __bf16* __restrict__ Apl,
                                                const __bf16* __restrict__ Bpl,
                                                float* __restrict__ U, int b0) {
  __shared__ __align__(16) char smem[36864];
  __bf16 (*As)[72] = (__bf16(*)[72])smem;
  __bf16 (*Bs)[72] = (__bf16(*)[72])(smem + 18432);
  const int b = b0 + blockIdx.z;
  const __bf16* Ab = Apl + (size_t)b * MP * KP;
  const __bf16* Bb = Bpl + (size_t)b * MP * KP;
  float* Ub = U + (size_t)blockIdx.z * (2560LL * 2560LL);
  const int t = threadIdx.x;
  const int q0 = blockIdx.y * 126 - 1, p0 = blockIdx.x * 126 - 1;
  const int lane = t & 63, w = t >> 6, wr = w >> 1, wc = w & 1;
  const int sr = t >> 1, ss = (t & 1) * 32;
  const int l31 = lane & 31, kb = (lane >> 5) * 8;
  const int arow = q0 + sr, brow = p0 + sr;
  const bool aok = (unsigned)arow < 2560u, bok = (unsigned)brow < 2560u;

  v16f acc[2][2];
#pragma unroll
  for (int i = 0; i < 2; ++i)
#pragma unroll
    for (int j = 0; j < 2; ++j)
#pragma unroll
      for (int e = 0; e < 16; ++e) acc[i][j][e] = 0.f;

  const float4 z4 = make_float4(0.f, 0.f, 0.f, 0.f);
  for (int kv = 0; kv < 768; kv += 64) {
    const int ak = kv < 256 ? kv : kv - 256;   // Ahi, Ahi, Alo
    const int bk = kv < 512 ? kv : kv - 512;   // Bhi, Blo, Bhi
    const __bf16* ga = Ab + (size_t)arow * KP + ak + ss;
    const __bf16* gb = Bb + (size_t)brow * KP + bk + ss;
    float4 a0 = aok ? *(const float4*)(ga)      : z4;
    float4 a1 = aok ? *(const float4*)(ga + 8)  : z4;
    float4 a2 = aok ? *(const float4*)(ga + 16) : z4;
    float4 a3 = aok ? *(const float4*)(ga + 24) : z4;
    float4 b0v = bok ? *(const float4*)(gb)      : z4;
    float4 b1v = bok ? *(const float4*)(gb + 8)  : z4;
    float4 b2v = bok ? *(const float4*)(gb + 16) : z4;
    float4 b3v = bok ? *(const float4*)(gb + 24) : z4;
    __syncthreads();
    *(float4*)(&As[sr][ss])      = a0;
    *(float4*)(&As[sr][ss + 8])  = a1;
    *(float4*)(&As[sr][ss + 16]) = a2;
    *(float4*)(&As[sr][ss + 24]) = a3;
    *(float4*)(&Bs[sr][ss])      = b0v;
    *(float4*)(&Bs[sr][ss + 8])  = b1v;
    *(float4*)(&Bs[sr][ss + 16]) = b2v;
    *(float4*)(&Bs[sr][ss + 24]) = b3v;
    __syncthreads();
#pragma unroll
    for (int kk = 0; kk < 4; ++kk) {
      const int ko = kk * 16 + kb;
      v8bf af0 = *(const v8bf*)(&As[wr * 64 + l31][ko]);
      v8bf af1 = *(const v8bf*)(&As[wr * 64 + 32 + l31][ko]);
      v8bf bg0 = *(const v8bf*)(&Bs[wc * 64 + l31][ko]);
      v8bf bg1 = *(const v8bf*)(&Bs[wc * 64 + 32 + l31][ko]);
      acc[0][0] = __builtin_amdgcn_mfma_f32_32x32x16_bf16(af0, bg0, acc[0][0], 0, 0, 0);
      acc[0][1] = __builtin_amdgcn_mfma_f32_32x32x16_bf16(af0, bg1, acc[0][1], 0, 0, 0);
      acc[1][0] = __builtin_amdgcn_mfma_f32_32x32x16_bf16(af1, bg0, acc[1][0], 0, 0, 0);
      acc[1][1] = __builtin_amdgcn_mfma_f32_32x32x16_bf16(af1, bg1, acc[1][1], 0, 0, 0);
    }
  }

  // ---- epilogue: dump S tile to LDS in 65-row halves, emit U interior ----
  float (*Sd)[128] = (float(*)[128])smem;
#pragma unroll
  for (int h = 0; h < 2; ++h) {
    const int rlo = h * 63;
    __syncthreads();
#pragma unroll
    for (int mf = 0; mf < 2; ++mf)
#pragma unroll
      for (int nf = 0; nf < 2; ++nf) {
        const int col = wc * 64 + nf * 32 + l31;
#pragma unroll
        for (int r16 = 0; r16 < 16; ++r16) {
          const int row = wr * 64 + mf * 32 + (r16 & 3) + 8 * (r16 >> 2) + 4 * (lane >> 5);
          const int lr = row - rlo;
          if (lr >= 0 && lr < 65) Sd[lr][col] = acc[mf][nf][r16];
        }
      }
    __syncthreads();
    for (int idx = t; idx < 63 * 126; idx += 256) {
      const int lr = idx / 126 + 1;            // 1..63
      const int ce = idx - (lr - 1) * 126 + 1; // 1..126
      const int gq = q0 + rlo + lr;
      const int gp = p0 + ce;
      if ((unsigned)gq < 2560u && (unsigned)gp < 2560u)
        Ub[(size_t)gq * 2560 + gp] = Sd[lr - 1][ce - 1] + Sd[lr][ce] + Sd[lr + 1][ce + 1];
    }
  }
}

__device__ __forceinline__ void top2merge(float& b1, int& i1, float& b2, int& i2,
                                          float o1, int oj1, float o2, int oj2) {
  if (o1 > b1 || (o1 == b1 && oj1 < i1)) {
    float t1 = b1; int tj = i1;
    b1 = o1; i1 = oj1;
    if (o2 > t1 || (o2 == t1 && oj2 < tj)) { b2 = o2; i2 = oj2; }
    else { b2 = t1; i2 = tj; }
  } else if (o1 > b2 || (o1 == b2 && oj1 < i2)) {
    b2 = o1; i2 = oj1;
  }
}

// ---- direct-read argmax on U: no LDS staging, no barriers in the scan.
// Block = 4x4 query tile x one of 5 key splits (512 keys, 2 chunks of 256).
// rel[q][p] = U[qp-50][p-50] + U[qp][p] + U[qp+50][p+50]; qp = Q0 + 50e + a,
// so all 48 loads per chunk are constant offsets off one per-thread base.
// OOB cols only occur for NaN-normed pad keys and stay inside the U slab.
__global__ __launch_bounds__(256) void k_argmax_d(const float* __restrict__ U,
                                                  const float* __restrict__ iknp,
                                                  int* __restrict__ cand,
                                                  float* __restrict__ candv, int b0) {
  __shared__ float smv[16][4][2];
  __shared__ int   smi[16][4][2];
  const int zb = blockIdx.z / 5, split = blockIdx.z - zb * 5;
  const int b = b0 + zb;
  const float* Ub = U + (size_t)zb * (2560LL * 2560LL);
  const int qy0 = blockIdx.y * 4, qx0 = blockIdx.x * 4;
  const int Q0 = (qy0 + 1) * 50 + qx0 + 1;
  const int t = threadIdx.x, lane = t & 63, wv = t >> 6;

  float b1[16], b2[16]; int i1[16], i2[16];
#pragma unroll
  for (int i = 0; i < 16; ++i) { b1[i] = -3e38f; b2[i] = -3e38f; i1[i] = 0x3fffffff; i2[i] = 0x3fffffff; }

#pragma unroll
  for (int cc = 0; cc < 2; ++cc) {
    const int P0 = split * 512 + cc * 256;
    const int p = P0 + t;
    const float ikv = iknp[b * MP + p];
    const float* baseP = Ub + (size_t)Q0 * 2560 + p;
#pragma unroll
    for (int e = 0; e < 4; ++e)
#pragma unroll
      for (int a = 0; a < 4; ++a) {
        const ptrdiff_t o = (ptrdiff_t)(50 * e + a) * 2560;
        const float vm = baseP[o - 50 * 2560 - 50];
        const float v0 = baseP[o];
        const float vp = baseP[o + 50 * 2560 + 50];
        const float v = (vm + v0 + vp) * ikv;  // NaN at invalid keys
        const int qi = e * 4 + a;
        if (v > b1[qi]) { b2[qi] = b1[qi]; i2[qi] = i1[qi]; b1[qi] = v; i1[qi] = p; }
        else if (v > b2[qi]) { b2[qi] = v; i2[qi] = p; }
      }
  }

#pragma unroll
  for (int qi = 0; qi < 16; ++qi) {
    float x1 = b1[qi], x2 = b2[qi]; int j1 = i1[qi], j2 = i2[qi];
#pragma unroll
    for (int off = 32; off; off >>= 1) {
      float o1 = __shfl_down(x1, off), o2 = __shfl_down(x2, off);
      int oj1 = __shfl_down(j1, off), oj2 = __shfl_down(j2, off);
      top2merge(x1, j1, x2, j2, o1, oj1, o2, oj2);
    }
    if (lane == 0) { smv[qi][wv][0] = x1; smv[qi][wv][1] = x2; smi[qi][wv][0] = j1; smi[qi][wv][1] = j2; }
  }
  __syncthreads();
  if (t < 16) {
    float x1 = smv[t][0][0], x2 = smv[t][0][1]; int j1 = smi[t][0][0], j2 = smi[t][0][1];
#pragma unroll
    for (int w2 = 1; w2 < 4; ++w2)
      top2merge(x1, j1, x2, j2, smv[t][w2][0], smi[t][w2][0], smv[t][w2][1], smi[t][w2][1]);
    // padded idx -> valid idx
    int my1 = j1 / 50, my2 = j2 / 50;
    int m1 = (my1 - 1) * 48 + (j1 - my1 * 50 - 1);
    int m2 = (my2 - 1) * 48 + (j2 - my2 * 50 - 1);
    const int q = (qy0 + (t >> 2)) * 48 + qx0 + (t & 3);
    const size_t base = ((size_t)b * HW3 + q) * 10 + split * 2;
    cand[base] = m1; cand[base + 1] = m2;
    candv[base] = x1; candv[base + 1] = x2;
  }
}

// ---- final pick: fast path on clear gaps, exact f32 dots only on near-ties ----
__global__ __launch_bounds__(256) void k_pick(const float* __restrict__ imgT,
                                              const float* __restrict__ refT,
                                              const float* __restrict__ ikn,
                                              const float* __restrict__ iqn,
                                              const int* __restrict__ cand,
                                              const float* __restrict__ candv,
                                              int* __restrict__ ridx,
                                              float* __restrict__ outS) {
  const int t = threadIdx.x, lane = t & 63, wv = t >> 6;
  const int qg = blockIdx.x * 4 + wv;
  const int b = qg / HW3, q = qg - b * HW3;
  int m1 = 0, m2 = 0; float v1 = -3e38f, v2 = -3e38f;
#pragma unroll
  for (int s = 0; s < 10; ++s) {
    int ci = cand[(size_t)qg * 10 + s];
    float cv = candv[(size_t)qg * 10 + s];
    if (cv > v1 || (cv == v1 && ci < m1)) {
      float tv = v1; int tj = m1;
      v1 = cv; m1 = ci;
      if (tv > v2 || (tv == v2 && tj < m2)) { v2 = tv; m2 = tj; }
    } else if (cv > v2 || (cv == v2 && ci < m2)) { v2 = cv; m2 = ci; }
  }
  int win = m1; float wval = v1;
  if (v1 - v2 <= 1e-5f * fmaxf(fabsf(v1), 1.0f)) {
    // exact rescore of m1, m2
    const int qy = q / 48, qx = q - qy * 48;
    const float* iT = imgT + (size_t)b * HW3 * 256;
    const float* rT = refT + (size_t)b * HW3 * 256;
    const int p1y = m1 / 48, p1x = m1 - p1y * 48;
    const int p2y = m2 / 48, p2x = m2 - p2y * 48;
    float s1 = 0.f, s2 = 0.f;
    for (int dy = -1; dy <= 1; ++dy) {
      int yq = qy + dy; if (yq < 0 || yq >= 48) continue;
      for (int dx = -1; dx <= 1; ++dx) {
        int xq = qx + dx; if (xq < 0 || xq >= 48) continue;
        const float* qrow = iT + (size_t)(yq * 48 + xq) * 256;
        int y1 = p1y + dy, x1 = p1x + dx, y2 = p2y + dy, x2 = p2x + dx;
        bool k1 = (y1 >= 0 && y1 < 48 && x1 >= 0 && x1 < 48);
        bool k2 = (y2 >= 0 && y2 < 48 && x2 >= 0 && x2 < 48);
        const float* r1 = rT + (size_t)(k1 ? y1 * 48 + x1 : 0) * 256;
        const float* r2 = rT + (size_t)(k2 ? y2 * 48 + x2 : 0) * 256;
#pragma unroll
        for (int j = 0; j < 4; ++j) {
          float qv = qrow[lane + j * 64];
          if (k1) s1 = fmaf(qv, r1[lane + j * 64], s1);
          if (k2) s2 = fmaf(qv, r2[lane + j * 64], s2);
        }
      }
    }
#pragma unroll
    for (int off = 32; off; off >>= 1) {
      s1 += __shfl_down(s1, off);
      s2 += __shfl_down(s2, off);
    }
    float e1 = s1 * ikn[b * HW3 + m1], e2 = s2 * ikn[b * HW3 + m2];
    if (e2 > e1 || (e2 == e1 && m2 < m1)) { win = m2; wval = e2; }
    else { win = m1; wval = e1; }
  }
  if (lane == 0) {
    ridx[b * HW3 + q] = win;
    outS[qg] = wval * iqn[b * HW3 + q];
  }
}

// ---- gather+fold in channel-last, coalesced, LDS transpose on write ----
__global__ __launch_bounds__(256) void k_foldgather(const float* __restrict__ t,
                                                    const int* __restrict__ ridx,
                                                    float* __restrict__ out,
                                                    int C, int H, int sc, int b0) {
  __shared__ int   soff[64][9];
  __shared__ float sicnt[64];
  __shared__ float tr[64][65];
  const int HW = H * H;
  const int b = b0 + blockIdx.y;
  const float* tb = t + (size_t)blockIdx.y * HW * C;
  const int* rb = ridx + b * HW3;
  const int pix0 = blockIdx.x * 64;

  for (int e = threadIdx.x; e < 576; e += 256) {
    int op = e / 9, tap = e - op * 9;
    int pix = pix0 + op;
    int h = pix / H, w = pix - h * H;
    int hi = h / sc, hr = h - hi * sc;
    int wi = w / sc, wr = w - wi * sc;
    int ii = tap / 3, jj = tap - ii * 3;
    int oy = hi + 1 - ii, ox = wi + 1 - jj;
    int off = -1;
    if (oy >= 0 && oy < 48 && ox >= 0 && ox < 48) {
      int m = rb[oy * 48 + ox];
      int my = m / 48, mx = m - my * 48;
      int y = sc * (my - 1 + ii) + hr;
      int x = sc * (mx - 1 + jj) + wr;
      if (y >= 0 && y < H && x >= 0 && x < H) off = y * H + x;
    }
    soff[op][tap] = off;
    if (tap == 0) {
      int cnt = 0;
#pragma unroll
      for (int i2 = 0; i2 < 3; ++i2)
#pragma unroll
        for (int j2 = 0; j2 < 3; ++j2) {
          int oy2 = hi + 1 - i2, ox2 = wi + 1 - j2;
          if (oy2 >= 0 && oy2 < 48 && ox2 >= 0 && ox2 < 48) ++cnt;
        }
      sicnt[op] = 1.0f / (float)cnt;
    }
  }
  __syncthreads();

  const int g = threadIdx.x >> 6, lane = threadIdx.x & 63;
  for (int c0 = 0; c0 < C; c0 += 64) {
#pragma unroll
    for (int o = 0; o < 16; ++o) {
      int op = g * 16 + o;
      float s = 0.f;
#pragma unroll
      for (int tp = 0; tp < 9; ++tp) {
        int off = soff[op][tp];
        if (off >= 0) s += tb[(size_t)off * C + c0 + lane];
      }
      tr[op][lane] = s * sicnt[op];
    }
    __syncthreads();
#pragma unroll
    for (int r = 0; r < 16; ++r) {
      int cl = r * 4 + g;
      out[((size_t)b * C + c0 + cl) * HW + pix0 + lane] = tr[lane][cl];
    }
    __syncthreads();
  }
}

extern "C" void kernel_launch(void* const* d_in, const int* in_sizes, int n_in,
                              void* d_out, int out_size, void* d_ws, size_t ws_size,
                              hipStream_t stream) {
  (void)in_sizes; (void)n_in; (void)out_size;
  const float* img = (const float*)d_in[0];
  const float* ref = (const float*)d_in[1];
  const float* cl1 = (const float*)d_in[2];   // [4,64,192,192]
  const float* cl2 = (const float*)d_in[3];   // [4,128,96,96]
  const float* cl3 = (const float*)d_in[4];   // [4,256,48,48]
  float* out = (float*)d_out;

  float* ws   = (float*)d_ws;
  float* ps_i = ws + O_PSI;
  float* ps_r = ws + O_PSR;
  float* ikn  = ws + O_IKN;
  float* iqn  = ws + O_IQN;
  int*   ridx = (int*)(ws + O_RIDX);
  float* iknp = ws + O_IKNP;
  int*   cand = (int*)(ws + O_CAND);
  float* candv = ws + O_CANDV;
  float* imgT = ws + O_IMGT;
  float* refT = ws + O_REFT;
  __bf16* Apl = (__bf16*)(ws + O_APL);
  __bf16* Bpl = (__bf16*)(ws + O_BPL);
  float* Um   = ws + O_U;

  // zero bf16 planes (pad pixels must be 0)
  hipMemsetAsync(ws + O_APL, 0, (size_t)(O_U - O_APL) * 4, stream);

  k_pixsq<<<144, 256, 0, stream>>>(img, ref, ps_i, ps_r);
  k_norm<<<36, 256, 0, stream>>>(ps_r, ps_i, ikn, iqn);
  k_normp<<<40, 256, 0, stream>>>(ps_r, iknp);
  k_padsplit<<<dim3(36, 4, 4), 256, 0, stream>>>(img, Apl);
  k_padsplit<<<dim3(36, 4, 4), 256, 0, stream>>>(ref, Bpl);
  k_tr<<<dim3(36, 4, 4), 256, 0, stream>>>(img, imgT, 256, HW3, 0);
  k_tr<<<dim3(36, 4, 4), 256, 0, stream>>>(ref, refT, 256, HW3, 0);

  const long long UPF = 2560LL * 2560LL;
  const long long availf = (long long)(ws_size / 4) - O_U;
  const int nb = (availf >= 4 * UPF) ? 4 : ((availf >= 2 * UPF) ? 2 : 1);
  for (int g = 0; g < 4; g += nb) {
    k_gemm_u<<<dim3(21, 21, nb), 256, 0, stream>>>(Apl, Bpl, Um, g);
    k_argmax_d<<<dim3(12, 12, nb * 5), 256, 0, stream>>>(Um, iknp, cand, candv, g);
  }
  k_pick<<<2304, 256, 0, stream>>>(imgT, refT, ikn, iqn, cand, candv, ridx, out);

  // folds (scratch reuses imgT.. region; search inputs dead by now)
  float* t = ws + O_IMGT;
  k_tr<<<dim3(36, 4, 4), 256, 0, stream>>>(cl3, t, 256, 2304, 0);
  k_foldgather<<<dim3(36, 4), 256, 0, stream>>>(t, ridx, out + 9216, 256, 48, 1, 0);
  k_tr<<<dim3(144, 2, 4), 256, 0, stream>>>(cl2, t, 128, 9216, 0);
  k_foldgather<<<dim3(144, 4), 256, 0, stream>>>(t, ridx, out + 2368512, 128, 96, 2, 0);
  k_tr<<<dim3(576, 1, 4), 256, 0, stream>>>(cl1, t, 64, 36864, 0);
  k_foldgather<<<dim3(576, 4), 256, 0, stream>>>(t, ridx, out + 7087104, 64, 192, 4, 0);
}